// Round 2
// baseline (141.838 us; speedup 1.0000x reference)
//
#include <hip/hip_runtime.h>
#include <stdint.h>

// BitNetLinear eval forward on MI355X (gfx950).
// M = B*S = 32768, K = 1024 (in_features), N = 1024 (out_features).
//
// R1: GEMM rewritten to 256x256 tile, BK=64, 8 waves, triple-buffered LDS
// with depth-2 prefetch and counted vmcnt(4) (T3+T4), per-phase barriers +
// setprio (T5), XOR chunk swizzle for 2-way ds_read_b128 (T2).

#define MK_M 32768
#define MK_K 1024
#define MK_N 1024

typedef __attribute__((ext_vector_type(4))) int int32x4;

// ---- workspace layout ----
#define WS_QW_OFF 4096
#define WS_QX_OFF (4096 + (1 << 20))
#define WS_NEEDED (WS_QX_OFF + (size_t)MK_M * MK_K)

__global__ void kmax_x(const float4* __restrict__ x4, unsigned* __restrict__ xmax, long n4) {
    float m = 0.f;
    long stride = (long)gridDim.x * blockDim.x;
    for (long i = (long)blockIdx.x * blockDim.x + threadIdx.x; i < n4; i += stride) {
        float4 v = x4[i];
        m = fmaxf(m, fmaxf(fmaxf(fabsf(v.x), fabsf(v.y)), fmaxf(fabsf(v.z), fabsf(v.w))));
    }
    #pragma unroll
    for (int off = 1; off < 64; off <<= 1) m = fmaxf(m, __shfl_xor(m, off));
    __shared__ float sm[4];
    int lane = threadIdx.x & 63, wid = threadIdx.x >> 6;
    if (lane == 0) sm[wid] = m;
    __syncthreads();
    if (threadIdx.x == 0) {
        float b = fmaxf(fmaxf(sm[0], sm[1]), fmaxf(sm[2], sm[3]));
        atomicMax(xmax, __float_as_uint(b));  // all values >= 0: uint order == float order
    }
}

__global__ void ksum_w(const float4* __restrict__ w4, double* __restrict__ partials) {
    double s = 0.0;
    for (int i = blockIdx.x * 256 + threadIdx.x; i < (1 << 18); i += 256 * 256) {
        float4 v = w4[i];
        s += (double)fabsf(v.x);
        s += (double)fabsf(v.y);
        s += (double)fabsf(v.z);
        s += (double)fabsf(v.w);
    }
    __shared__ double sd[256];
    sd[threadIdx.x] = s;
    __syncthreads();
    for (int h = 128; h > 0; h >>= 1) {
        if ((int)threadIdx.x < h) sd[threadIdx.x] += sd[threadIdx.x + h];
        __syncthreads();
    }
    if (threadIdx.x == 0) partials[blockIdx.x] = sd[0];
}

__global__ void kfin(const double* __restrict__ partials, const unsigned* __restrict__ xmax,
                     float* __restrict__ wscp, float* __restrict__ iscp) {
    if (threadIdx.x == 0 && blockIdx.x == 0) {
        double s = 0.0;
        for (int i = 0; i < 256; ++i) s += partials[i];
        *wscp = (float)(s / 1048576.0);               // mean|W| (2^20 elements)
        *iscp = __uint_as_float(*xmax) / 127.0f;      // fp32 divide, matches ref
    }
}

__global__ void kquant_w(const float4* __restrict__ w4, unsigned* __restrict__ qw,
                         const float* __restrict__ wscp) {
    float thr = 0.5f * (*wscp);
    int stride = gridDim.x * blockDim.x;
    for (int i = blockIdx.x * blockDim.x + threadIdx.x; i < (1 << 18); i += stride) {
        float4 v = w4[i];
        int q0 = (fabsf(v.x) > thr) ? (v.x > 0.f ? 1 : -1) : 0;
        int q1 = (fabsf(v.y) > thr) ? (v.y > 0.f ? 1 : -1) : 0;
        int q2 = (fabsf(v.z) > thr) ? (v.z > 0.f ? 1 : -1) : 0;
        int q3 = (fabsf(v.w) > thr) ? (v.w > 0.f ? 1 : -1) : 0;
        qw[i] = (q0 & 0xff) | ((q1 & 0xff) << 8) | ((q2 & 0xff) << 16) | ((q3 & 0xff) << 24);
    }
}

__global__ void kquant_x(const float4* __restrict__ x4, unsigned* __restrict__ qx,
                         const float* __restrict__ iscp, long n4) {
    float isc = *iscp;
    long stride = (long)gridDim.x * blockDim.x;
    for (long i = (long)blockIdx.x * blockDim.x + threadIdx.x; i < n4; i += stride) {
        float4 v = x4[i];
        float q0 = fminf(fmaxf(rintf(v.x / isc), -128.f), 127.f);
        float q1 = fminf(fmaxf(rintf(v.y / isc), -128.f), 127.f);
        float q2 = fminf(fmaxf(rintf(v.z / isc), -128.f), 127.f);
        float q3 = fminf(fmaxf(rintf(v.w / isc), -128.f), 127.f);
        int i0 = (int)q0, i1 = (int)q1, i2 = (int)q2, i3 = (int)q3;
        qx[i] = (i0 & 0xff) | ((i1 & 0xff) << 8) | ((i2 & 0xff) << 16) | ((i3 & 0xff) << 24);
    }
}

// ---- int8 GEMM: out[m][n] = sum_k qx[m][k] * qw[n][k] ----
// 256x256 tile, BK=64. 8 waves (2M x 4N), per-wave 128x64 output.
// LDS: 3 buffers x (A 16KB + B 16KB) = 96KB, depth-2 prefetch, vmcnt(4).
// Per K-tile: 4 phases, each = {6 ds_read_b128, 1 global_load_lds stage,
// barrier, 8 MFMA wrapped in setprio, barrier}.
// Swizzle: LDS rows are 64B (4 x 16B chunks); logical chunk ch of row r is
// stored at chunk ch ^ ((r>>1)&3). Stager pre-swizzles the GLOBAL source
// (gch = (t&3) ^ ((t>>3)&3)); gload LDS dest stays linear (rule 21).
// Readers (lanes 0..15 = 16 consecutive rows, same k-chunk) then hit 2-way
// bank aliasing only (free) instead of 8-way.
__global__ __launch_bounds__(512, 2) void kgemm(
    const char* __restrict__ qx, const char* __restrict__ qw,
    const float* __restrict__ bias, const float* __restrict__ wscp,
    const float* __restrict__ iscp, float* __restrict__ out)
{
    __shared__ __align__(16) char smem[3 * 32768];

    const int t = threadIdx.x;
    const int l = t & 63;
    const int w = t >> 6;          // 0..7
    const int wm = w >> 2;         // 0..1  (M half)
    const int wn = w & 3;          // 0..3  (N quarter)

    // XCD-bijective swizzle: 512 blocks, 8 XCDs, 64 contiguous per XCD.
    const int bid = blockIdx.x;
    const int wg = (bid & 7) * 64 + (bid >> 3);
    const int tm = wg >> 2, tn = wg & 3;     // 128 x 4 tiles
    const long m0 = (long)tm * 256;
    const int n0 = tn * 256;

    // staging per-thread constants (one 16B gload per thread per unit;
    // unit = 128 rows x 64B = 8KB = 512 threads x 16B)
    const int grow = t >> 2;                    // row within half-tile
    const int gch = (t & 3) ^ ((t >> 3) & 3);   // pre-swizzled global chunk
    const long goff = (long)grow * MK_K + gch * 16;
    const int loff = t * 16;                    // linear LDS offset in unit

    const char* gAt = qx + m0 * MK_K + goff;
    const char* gBt = qw + (long)n0 * MK_K + goff;

    int32x4 acc[8][4];
    #pragma unroll
    for (int mi = 0; mi < 8; ++mi)
        #pragma unroll
        for (int ni = 0; ni < 4; ++ni) acc[mi][ni] = (int32x4)0;

    // stage unit u (0/1 = A half, 2/3 = B half) of K-tile kt into buffer b
    auto stage = [&](int u, int kt, int b) {
        char* nbase = smem + b * 32768;
        const char* src;
        char* dst;
        if (u < 2) {
            src = gAt + (long)u * 128 * MK_K + kt * 64;
            dst = nbase + u * 8192 + loff;
        } else {
            src = gBt + (long)(u - 2) * 128 * MK_K + kt * 64;
            dst = nbase + 16384 + (u - 2) * 8192 + loff;
        }
        __builtin_amdgcn_global_load_lds(
            (const __attribute__((address_space(1))) void*)src,
            (__attribute__((address_space(3))) void*)dst, 16, 0, 0);
    };

    // prologue: tiles 0 and 1 into buffers 0 and 1 (8 gloads in flight)
    #pragma unroll
    for (int u = 0; u < 4; ++u) stage(u, 0, 0);
    #pragma unroll
    for (int u = 0; u < 4; ++u) stage(u, 1, 1);

    for (int kt = 0; kt < 16; ++kt) {
        // wait for K-tile kt's 4 units (issued 2 iters ago); keep the next
        // tile's 4 loads in flight — never drain vmcnt to 0 mid-loop (T4).
        if (kt < 15) asm volatile("s_waitcnt vmcnt(4)" ::: "memory");
        else         asm volatile("s_waitcnt vmcnt(0)" ::: "memory");
        __builtin_amdgcn_s_barrier();

        const int cb = kt % 3;
        const int nb = (kt + 2) % 3;
        const char* bufA = smem + cb * 32768;
        const char* bufB = bufA + 16384;
        const bool do_stage = (kt < 14);

        #pragma unroll
        for (int ph = 0; ph < 4; ++ph) {
            const int pm = ph >> 1, pn = ph & 1;   // C quadrant
            int32x4 af[4], bf[2];
            #pragma unroll
            for (int i = 0; i < 4; ++i) {
                int row = wm * 128 + (pm * 4 + i) * 16 + (l & 15);
                int ch = (l >> 4) ^ ((row >> 1) & 3);
                af[i] = *(const int32x4*)(bufA + row * 64 + ch * 16);
            }
            #pragma unroll
            for (int i = 0; i < 2; ++i) {
                int row = wn * 64 + (pn * 2 + i) * 16 + (l & 15);
                int ch = (l >> 4) ^ ((row >> 1) & 3);
                bf[i] = *(const int32x4*)(bufB + row * 64 + ch * 16);
            }
            if (do_stage) stage(ph, kt + 2, nb);   // 1 unit per phase
            __builtin_amdgcn_s_barrier();
            __builtin_amdgcn_s_setprio(1);
            #pragma unroll
            for (int mi = 0; mi < 4; ++mi)
                #pragma unroll
                for (int ni = 0; ni < 2; ++ni)
                    acc[pm * 4 + mi][pn * 2 + ni] = __builtin_amdgcn_mfma_i32_16x16x64_i8(
                        af[mi], bf[ni], acc[pm * 4 + mi][pn * 2 + ni], 0, 0, 0);
            __builtin_amdgcn_s_setprio(0);
            __builtin_amdgcn_s_barrier();
        }
    }

    // epilogue: C/D layout col = lane&15, row = (lane>>4)*4 + reg (verified R0)
    const float wsc = *wscp, isc = *iscp;
    const int crow = (l >> 4) * 4;
    const int ccol = l & 15;
    #pragma unroll
    for (int mi = 0; mi < 8; ++mi) {
        #pragma unroll
        for (int ni = 0; ni < 4; ++ni) {
            long r0 = m0 + wm * 128 + mi * 16 + crow;
            int c = n0 + wn * 64 + ni * 16 + ccol;
            float b = bias[c];
            #pragma unroll
            for (int j = 0; j < 4; ++j) {
                out[(r0 + j) * MK_N + c] = ((float)acc[mi][ni][j] * wsc) * isc + b;
            }
        }
    }
}

extern "C" void kernel_launch(void* const* d_in, const int* in_sizes, int n_in,
                              void* d_out, int out_size, void* d_ws, size_t ws_size,
                              hipStream_t stream) {
    const float* x = (const float*)d_in[0];
    const float* wt = (const float*)d_in[1];
    const float* bias = (const float*)d_in[2];
    float* out = (float*)d_out;

    if (ws_size < WS_NEEDED) return;

    char* ws = (char*)d_ws;
    unsigned* xmax = (unsigned*)ws;
    float* wscp = (float*)(ws + 4);
    float* iscp = (float*)(ws + 8);
    double* partials = (double*)(ws + 16);
    char* qw = ws + WS_QW_OFF;
    char* qx = ws + WS_QX_OFF;

    const long n_x = (long)in_sizes[0];   // 33554432
    const long n4_x = n_x >> 2;

    hipMemsetAsync(d_ws, 0, 16, stream);  // zero xmax_bits (capture-safe)

    kmax_x<<<2048, 256, 0, stream>>>((const float4*)x, xmax, n4_x);
    ksum_w<<<256, 256, 0, stream>>>((const float4*)wt, partials);
    kfin<<<1, 64, 0, stream>>>(partials, xmax, wscp, iscp);
    kquant_w<<<256, 256, 0, stream>>>((const float4*)wt, (unsigned*)qw, wscp);
    kquant_x<<<2048, 256, 0, stream>>>((const float4*)x, (unsigned*)qx, iscp, n4_x);

    const int grid = (MK_M / 256) * (MK_N / 256);  // 512
    kgemm<<<grid, 512, 0, stream>>>(qx, qw, bias, wscp, iscp, out);
}

// Round 3
// 109.884 us; speedup vs baseline: 1.2908x; 1.2908x over previous
//
#include <hip/hip_runtime.h>
#include <stdint.h>

// BitNetLinear eval forward on MI355X (gfx950).
// M = B*S = 32768, K = 1024 (in_features), N = 1024 (out_features).
//
// R2: GEMM keeps 256x256/BK=64/8-wave/triple-buffer/vmcnt(4) but loads ALL
// per-wave fragments (af[8], bf[4]) ONCE per K-tile and runs all 32 MFMAs in
// one cluster -> halves LDS read traffic (the R1 bottleneck), 1 barrier/K-tile.
// Also: absmax via per-block maxima array (no atomic, no memset dispatch).

#define MK_M 32768
#define MK_K 1024
#define MK_N 1024

typedef __attribute__((ext_vector_type(4))) int int32x4;

// ---- workspace layout ----
// [0]    float w_scale
// [4]    float i_scale
// [64]   float maxp[2048]     (per-block |x| maxima, fully rewritten each call)
// [8448] double partials[256] (|W| partial sums, fully rewritten each call)
// [16384]        qw (1 MB)
// [16384 + 1 MB] qx (32 MB)
#define WS_MAXP_OFF 64
#define WS_PART_OFF 8448
#define WS_QW_OFF 16384
#define WS_QX_OFF (16384 + (1 << 20))
#define WS_NEEDED (WS_QX_OFF + (size_t)MK_M * MK_K)

__global__ void kmax_x(const float4* __restrict__ x4, float* __restrict__ maxp, long n4) {
    float m = 0.f;
    long stride = (long)gridDim.x * blockDim.x;
    for (long i = (long)blockIdx.x * blockDim.x + threadIdx.x; i < n4; i += stride) {
        float4 v = x4[i];
        m = fmaxf(m, fmaxf(fmaxf(fabsf(v.x), fabsf(v.y)), fmaxf(fabsf(v.z), fabsf(v.w))));
    }
    #pragma unroll
    for (int off = 1; off < 64; off <<= 1) m = fmaxf(m, __shfl_xor(m, off));
    __shared__ float sm[4];
    int lane = threadIdx.x & 63, wid = threadIdx.x >> 6;
    if (lane == 0) sm[wid] = m;
    __syncthreads();
    if (threadIdx.x == 0) maxp[blockIdx.x] = fmaxf(fmaxf(sm[0], sm[1]), fmaxf(sm[2], sm[3]));
}

__global__ void ksum_w(const float4* __restrict__ w4, double* __restrict__ partials) {
    double s = 0.0;
    for (int i = blockIdx.x * 256 + threadIdx.x; i < (1 << 18); i += 256 * 256) {
        float4 v = w4[i];
        s += (double)fabsf(v.x);
        s += (double)fabsf(v.y);
        s += (double)fabsf(v.z);
        s += (double)fabsf(v.w);
    }
    __shared__ double sd[256];
    sd[threadIdx.x] = s;
    __syncthreads();
    for (int h = 128; h > 0; h >>= 1) {
        if ((int)threadIdx.x < h) sd[threadIdx.x] += sd[threadIdx.x + h];
        __syncthreads();
    }
    if (threadIdx.x == 0) partials[blockIdx.x] = sd[0];
}

// single wave: reduce 2048 maxima (order-independent) + 256 double partials
// (fixed-order tree -> deterministic)
__global__ void kfin(const double* __restrict__ partials, const float* __restrict__ maxp,
                     float* __restrict__ wscp, float* __restrict__ iscp) {
    int t = threadIdx.x;  // 0..63
    float m = 0.f;
    #pragma unroll
    for (int j = 0; j < 32; ++j) m = fmaxf(m, maxp[t + 64 * j]);
    double s = partials[4 * t] + partials[4 * t + 1] + partials[4 * t + 2] + partials[4 * t + 3];
    #pragma unroll
    for (int off = 1; off < 64; off <<= 1) {
        m = fmaxf(m, __shfl_xor(m, off));
        s = s + __shfl_xor(s, off);
    }
    if (t == 0) {
        *wscp = (float)(s / 1048576.0);   // mean|W| over 2^20 elements
        *iscp = m / 127.0f;               // fp32 divide, matches ref
    }
}

__global__ void kquant_w(const float4* __restrict__ w4, unsigned* __restrict__ qw,
                         const float* __restrict__ wscp) {
    float thr = 0.5f * (*wscp);
    int stride = gridDim.x * blockDim.x;
    for (int i = blockIdx.x * blockDim.x + threadIdx.x; i < (1 << 18); i += stride) {
        float4 v = w4[i];
        int q0 = (fabsf(v.x) > thr) ? (v.x > 0.f ? 1 : -1) : 0;
        int q1 = (fabsf(v.y) > thr) ? (v.y > 0.f ? 1 : -1) : 0;
        int q2 = (fabsf(v.z) > thr) ? (v.z > 0.f ? 1 : -1) : 0;
        int q3 = (fabsf(v.w) > thr) ? (v.w > 0.f ? 1 : -1) : 0;
        qw[i] = (q0 & 0xff) | ((q1 & 0xff) << 8) | ((q2 & 0xff) << 16) | ((q3 & 0xff) << 24);
    }
}

__global__ void kquant_x(const float4* __restrict__ x4, unsigned* __restrict__ qx,
                         const float* __restrict__ iscp, long n4) {
    float isc = *iscp;
    long stride = (long)gridDim.x * blockDim.x;
    for (long i = (long)blockIdx.x * blockDim.x + threadIdx.x; i < n4; i += stride) {
        float4 v = x4[i];
        // IEEE divide + rint (half-to-even) to match jnp.round(x / i_scale)
        float q0 = fminf(fmaxf(rintf(v.x / isc), -128.f), 127.f);
        float q1 = fminf(fmaxf(rintf(v.y / isc), -128.f), 127.f);
        float q2 = fminf(fmaxf(rintf(v.z / isc), -128.f), 127.f);
        float q3 = fminf(fmaxf(rintf(v.w / isc), -128.f), 127.f);
        int i0 = (int)q0, i1 = (int)q1, i2 = (int)q2, i3 = (int)q3;
        qx[i] = (i0 & 0xff) | ((i1 & 0xff) << 8) | ((i2 & 0xff) << 16) | ((i3 & 0xff) << 24);
    }
}

// ---- int8 GEMM: out[m][n] = sum_k qx[m][k] * qw[n][k] ----
// 256x256 tile, BK=64. 8 waves (2M x 4N), per-wave 128x64 output.
// Per K-tile (one barrier region): 12 ds_read_b128 (af[8], bf[4]) loaded ONCE,
// 4 global_load_lds stage units for tile kt+2, 32 MFMAs in one setprio cluster.
// Triple-buffered LDS (96 KB), depth-2 prefetch, counted vmcnt(4) (T3+T4).
// Swizzle (verified R1, SQ_LDS_BANK_CONFLICT=0): chunk ch of row r stored at
// ch ^ ((r>>1)&3); staged by pre-swizzling the GLOBAL source, LDS dest linear.
__global__ __launch_bounds__(512, 2) void kgemm(
    const char* __restrict__ qx, const char* __restrict__ qw,
    const float* __restrict__ bias, const float* __restrict__ wscp,
    const float* __restrict__ iscp, float* __restrict__ out)
{
    __shared__ __align__(16) char smem[3 * 32768];

    const int t = threadIdx.x;
    const int l = t & 63;
    const int w = t >> 6;          // 0..7
    const int wm = w >> 2;         // 0..1  (M half)
    const int wn = w & 3;          // 0..3  (N quarter)

    // XCD-bijective swizzle: 512 blocks, 8 XCDs, 64 contiguous per XCD.
    const int bid = blockIdx.x;
    const int wg = (bid & 7) * 64 + (bid >> 3);
    const int tm = wg >> 2, tn = wg & 3;
    const long m0 = (long)tm * 256;
    const int n0 = tn * 256;

    // staging constants: unit = 128 rows x 64B = 8KB = 512 threads x 16B
    const int grow = t >> 2;
    const int gch = (t & 3) ^ ((t >> 3) & 3);   // pre-swizzled global chunk
    const long goff = (long)grow * MK_K + gch * 16;
    const int loff = t * 16;

    const char* gAt = qx + m0 * MK_K + goff;
    const char* gBt = qw + (long)n0 * MK_K + goff;

    int32x4 acc[8][4];
    #pragma unroll
    for (int mi = 0; mi < 8; ++mi)
        #pragma unroll
        for (int ni = 0; ni < 4; ++ni) acc[mi][ni] = (int32x4)0;

    auto stage = [&](int u, int kt, int b) {
        char* nbase = smem + b * 32768;
        const char* src;
        char* dst;
        if (u < 2) {
            src = gAt + (long)u * 128 * MK_K + kt * 64;
            dst = nbase + u * 8192 + loff;
        } else {
            src = gBt + (long)(u - 2) * 128 * MK_K + kt * 64;
            dst = nbase + 16384 + (u - 2) * 8192 + loff;
        }
        __builtin_amdgcn_global_load_lds(
            (const __attribute__((address_space(1))) void*)src,
            (__attribute__((address_space(3))) void*)dst, 16, 0, 0);
    };

    // prologue: tiles 0 and 1 into buffers 0 and 1 (8 loads in flight)
    #pragma unroll
    for (int u = 0; u < 4; ++u) stage(u, 0, 0);
    #pragma unroll
    for (int u = 0; u < 4; ++u) stage(u, 1, 1);

    for (int kt = 0; kt < 16; ++kt) {
        // wait for tile kt's 4 units; keep tile kt+1's 4 in flight (T4).
        if (kt < 15) asm volatile("s_waitcnt vmcnt(4)" ::: "memory");
        else         asm volatile("s_waitcnt vmcnt(0)" ::: "memory");
        __builtin_amdgcn_s_barrier();
        // After this barrier: buffer (kt+2)%3 == (kt-1)%3 is fully consumed
        // (its readers' MFMAs issued before they reached the barrier).

        const int cb = kt % 3;
        const int nb = (kt + 2) % 3;
        const char* bufA = smem + cb * 32768;
        const char* bufB = bufA + 16384;

        int32x4 af[8], bf[4];
        #pragma unroll
        for (int i = 0; i < 8; ++i) {
            int row = wm * 128 + i * 16 + (l & 15);
            int ch = (l >> 4) ^ ((row >> 1) & 3);
            af[i] = *(const int32x4*)(bufA + row * 64 + ch * 16);
        }
        #pragma unroll
        for (int i = 0; i < 4; ++i) {
            int row = wn * 64 + i * 16 + (l & 15);
            int ch = (l >> 4) ^ ((row >> 1) & 3);
            bf[i] = *(const int32x4*)(bufB + row * 64 + ch * 16);
        }
        if (kt < 14) {
            #pragma unroll
            for (int u = 0; u < 4; ++u) stage(u, kt + 2, nb);
        }
        __builtin_amdgcn_s_setprio(1);
        #pragma unroll
        for (int mi = 0; mi < 8; ++mi)
            #pragma unroll
            for (int ni = 0; ni < 4; ++ni)
                acc[mi][ni] = __builtin_amdgcn_mfma_i32_16x16x64_i8(
                    af[mi], bf[ni], acc[mi][ni], 0, 0, 0);
        __builtin_amdgcn_s_setprio(0);
    }

    // epilogue: C/D layout col = lane&15, row = (lane>>4)*4 + reg (verified)
    const float wsc = *wscp, isc = *iscp;
    const int crow = (l >> 4) * 4;
    const int ccol = l & 15;
    #pragma unroll
    for (int mi = 0; mi < 8; ++mi) {
        #pragma unroll
        for (int ni = 0; ni < 4; ++ni) {
            long r0 = m0 + wm * 128 + mi * 16 + crow;
            int c = n0 + wn * 64 + ni * 16 + ccol;
            float b = bias[c];
            #pragma unroll
            for (int j = 0; j < 4; ++j) {
                out[(r0 + j) * MK_N + c] = ((float)acc[mi][ni][j] * wsc) * isc + b;
            }
        }
    }
}

extern "C" void kernel_launch(void* const* d_in, const int* in_sizes, int n_in,
                              void* d_out, int out_size, void* d_ws, size_t ws_size,
                              hipStream_t stream) {
    const float* x = (const float*)d_in[0];
    const float* wt = (const float*)d_in[1];
    const float* bias = (const float*)d_in[2];
    float* out = (float*)d_out;

    if (ws_size < WS_NEEDED) return;

    char* ws = (char*)d_ws;
    float* wscp = (float*)(ws + 0);
    float* iscp = (float*)(ws + 4);
    float* maxp = (float*)(ws + WS_MAXP_OFF);
    double* partials = (double*)(ws + WS_PART_OFF);
    char* qw = ws + WS_QW_OFF;
    char* qx = ws + WS_QX_OFF;

    const long n_x = (long)in_sizes[0];   // 33554432
    const long n4_x = n_x >> 2;

    kmax_x<<<2048, 256, 0, stream>>>((const float4*)x, maxp, n4_x);
    ksum_w<<<256, 256, 0, stream>>>((const float4*)wt, partials);
    kfin<<<1, 64, 0, stream>>>(partials, maxp, wscp, iscp);
    kquant_w<<<256, 256, 0, stream>>>((const float4*)wt, (unsigned*)qw, wscp);
    kquant_x<<<2048, 256, 0, stream>>>((const float4*)x, (unsigned*)qx, iscp, n4_x);

    const int grid = (MK_M / 256) * (MK_N / 256);  // 512
    kgemm<<<grid, 512, 0, stream>>>(qx, qw, bias, wscp, iscp, out);
}